// Round 5
// baseline (61615.430 us; speedup 1.0000x reference)
//
#include <hip/hip_runtime.h>

#define BB 16
#define SS 256
#define NVOCAB 32000
#define NEMB 300

// ---- recurrence geometry ----
#define CHUNK 6            // h-indices per block (multiple of 3 -> chunk-aligned)
#define RROWS 24           // gate rows per block
#define NT 384             // threads per rec block (= RROWS*16)
#define NSTR 384           // hx chunk stride per batch row (allocation)

typedef float f4_t __attribute__((ext_vector_type(4)));
typedef unsigned int u4_t __attribute__((ext_vector_type(4)));

// LLC-coherent 16B ops (sc0|sc1: bypass non-coherent L1/L2, served by MALL).
__device__ __forceinline__ void llc_load_u4(u4_t& v, const u4_t* p) {
    asm volatile("global_load_dwordx4 %0, %1, off sc0 sc1" : "=v"(v) : "v"(p));
}
__device__ __forceinline__ void llc_store_u4(u4_t* p, const u4_t& v) {
    asm volatile("global_store_dwordx4 %0, %1, off sc0 sc1" :: "v"(p), "v"(v) : "memory");
}
__device__ __forceinline__ void anchor_u4(u4_t& v) { asm volatile("" : "+v"(v)); }

// ============================ embedding ============================
__global__ void embed_kernel(const int* __restrict__ ids,
                             const float* __restrict__ emb,
                             float* __restrict__ x0) {
    int bs = blockIdx.x;                       // r = b*S+s
    int id = ids[bs];
    const float* row = emb + (size_t)id * NEMB;
    float* out = x0 + (size_t)bs * NEMB;
    const float scale = 17.320508075688772f;   // sqrt(300)
    for (int e = threadIdx.x; e < NEMB; e += blockDim.x)
        out[e] = row[e] * scale;
}

// ============================ GEMM: C = A[M,K] * W[N,K]^T (+bias) ============================
#define TM 64
#define TN 64
#define KT 16
#define LDT 68

__global__ __launch_bounds__(256) void gemm_xw(
        const float* __restrict__ A, const float* __restrict__ W,
        float* __restrict__ C, int N, int K,
        const float* __restrict__ bias_i, const float* __restrict__ bias_h,
        int permuted) {
    __shared__ __align__(16) float As[KT][LDT];
    __shared__ __align__(16) float Bs[KT][LDT];
    const int n0 = blockIdx.x * TN;
    const int m0 = blockIdx.y * TM;
    const int t  = threadIdx.x;
    const int tk = t & 15;
    const int tm = t >> 4;
    const int tx = t & 15;
    const int ty = t >> 4;
    float acc[4][4] = {};

    for (int k0 = 0; k0 < K; k0 += KT) {
        int k = k0 + tk;
        bool kok = (k < K);
        #pragma unroll
        for (int i = 0; i < 4; i++) {
            int m = tm + i * 16;
            As[tk][m] = kok ? A[(size_t)(m0 + m) * K + k] : 0.f;
            int n = n0 + m;
            Bs[tk][m] = (kok && n < N) ? W[(size_t)n * K + k] : 0.f;
        }
        __syncthreads();
        #pragma unroll
        for (int kk = 0; kk < KT; kk++) {
            float4 a = *reinterpret_cast<const float4*>(&As[kk][ty * 4]);
            float4 b = *reinterpret_cast<const float4*>(&Bs[kk][tx * 4]);
            acc[0][0] += a.x * b.x; acc[0][1] += a.x * b.y; acc[0][2] += a.x * b.z; acc[0][3] += a.x * b.w;
            acc[1][0] += a.y * b.x; acc[1][1] += a.y * b.y; acc[1][2] += a.y * b.z; acc[1][3] += a.y * b.w;
            acc[2][0] += a.z * b.x; acc[2][1] += a.z * b.y; acc[2][2] += a.z * b.z; acc[2][3] += a.z * b.w;
            acc[3][0] += a.w * b.x; acc[3][1] += a.w * b.y; acc[3][2] += a.w * b.z; acc[3][3] += a.w * b.w;
        }
        __syncthreads();
    }

    #pragma unroll
    for (int i = 0; i < 4; i++) {
        int m = m0 + ty * 4 + i;
        #pragma unroll
        for (int j = 0; j < 4; j++) {
            int n = n0 + tx * 4 + j;
            if (n < N) {
                float v = acc[i][j];
                if (bias_i) v += bias_i[n] + bias_h[n];
                size_t idx;
                if (permuted) {
                    int b_ = m >> 8;        // S = 256
                    int s_ = m & 255;
                    idx = ((size_t)s_ * BB + b_) * (size_t)N + n;
                } else {
                    idx = (size_t)m * (size_t)N + n;
                }
                C[idx] = v;
            }
        }
    }
}

// ============================ persistent LSTM recurrence ============================
// Weight-stationary: thread (row, ks) holds W[row][k-slice] in VGPRs for all
// 256 steps (zero LDS W-reads). h exchanged as 16B {h0,h1,h2,tag} chunks via
// sc0|sc1 stores/loads (round-4 scheme, race-free). Per step: stage h tile ->
// per-thread partial dots (ds_read_b128 h, 4-way row-broadcast, W in regs) ->
// k-slice reduction via padded LDS -> gates -> publish.
template<int NCHW, int KP, int PH, int E>
__global__ __launch_bounds__(NT, 1) void lstm_rec(
        const float* __restrict__ Whh,   // [4H][H]
        const float* __restrict__ xg,    // [S][B][4H]
        float* __restrict__ xout,        // [B][S][H]
        u4_t* __restrict__ hx,           // [2][16][NSTR] chunks
        int H, unsigned TB) {
    constexpr int PHC = NCHW / PH;       // chunks per batch row per phase
    constexpr int PW  = KP / PH;         // floats per phase
    constexpr int SW  = PW / 16;         // floats per thread slice per phase
    constexpr int NQ  = SW / 4;          // f4 per thread slice per phase
    constexpr int LDH = KP + 4;          // h tile row stride
    constexpr int PBS = RROWS * 16 + 4;  // pbuf ks-stride (388)
    extern __shared__ __align__(16) float lds[];
    float* ht    = lds;                    // [16][LDH]
    float* pbuf  = ht + 16 * LDH;          // [16][PBS]
    float* gbuf2 = pbuf + 16 * PBS;        // [384]
    float* cbuf  = gbuf2 + NT;             // [96]
    float* hlx   = cbuf + 96;              // [96]

    const int t   = threadIdx.x;
    const int h0  = blockIdx.x * CHUNK;
    const int G4  = 4 * H;
    const int ks  = t & 15;
    const int row = t >> 4;               // 0..23
    const int g_  = row / CHUNK;
    const int l_  = row - g_ * CHUNK;
    const bool wvalid = (h0 + l_) < H;
    const int grow = wvalid ? (g_ * H + h0 + l_) : 0;

    // ---- one-time: W slice into registers ----
    f4_t w[PH][NQ];
    #pragma unroll
    for (int p = 0; p < PH; p++) {
        #pragma unroll
        for (int q = 0; q < NQ; q++) {
            int k = p * PW + ks * SW + 4 * q;
            f4_t v; v.x = 0.f; v.y = 0.f; v.z = 0.f; v.w = 0.f;
            if (wvalid) {
                const float* src = Whh + (size_t)grow * H;
                if (k + 0 < H) v.x = src[k + 0];
                if (k + 1 < H) v.y = src[k + 1];
                if (k + 2 < H) v.z = src[k + 2];
                if (k + 3 < H) v.w = src[k + 3];
            }
            w[p][q] = v;
        }
    }

    // zero ht (covers the never-staged pad region) and c state
    for (int i = t; i < 16 * LDH; i += NT) ht[i] = 0.f;
    if (t < 96) cbuf[t] = 0.f;
    __syncthreads();

    // reducer role: thread (row, b=ks)
    const float* xgp = xg + (size_t)ks * G4 + grow;

    // staging chunk coordinates: idx -> (batch row bb, in-phase chunk sj)
    int  sb[E]; int sj[E]; bool sa[E];
    #pragma unroll
    for (int e = 0; e < E; e++) {
        int idx = t + e * NT;
        sa[e] = idx < 16 * PHC;
        if (!sa[e]) idx = 0;
        sb[e] = idx / PHC;
        sj[e] = idx - sb[e] * PHC;
    }
    u4_t u[E];

    auto issue = [&](const u4_t* base, int p) {
        #pragma unroll
        for (int e = 0; e < E; e++)
            if (sa[e]) llc_load_u4(u[e], base + sb[e] * NSTR + p * PHC + sj[e]);
    };

    for (int s = 0; s < SS; s++) {
        const u4_t* hcb = hx + (size_t)(s & 1) * (16 * NSTR);        // consume
        u4_t*       hpb = hx + (size_t)((s + 1) & 1) * (16 * NSTR);  // produce
        float xgv = wvalid ? xgp[(size_t)s * 16 * G4] : 0.f;         // prefetch
        float p_[16];
        #pragma unroll
        for (int b = 0; b < 16; b++) p_[b] = 0.f;

        if (s > 0) {
            const unsigned tgt = TB + (unsigned)s;
            #pragma unroll
            for (int p = 0; p < PH; p++) {
                // retry-wait the in-flight loads of phase p
                for (;;) {
                    asm volatile("s_waitcnt vmcnt(0)" ::: "memory");
                    #pragma unroll
                    for (int e = 0; e < E; e++) anchor_u4(u[e]);
                    bool pend = false;
                    #pragma unroll
                    for (int e = 0; e < E; e++)
                        if (sa[e] && u[e].w < tgt) {
                            pend = true;
                            llc_load_u4(u[e], hcb + sb[e] * NSTR + p * PHC + sj[e]);
                        }
                    if (!pend) break;
                }
                // unpack to LDS tile (k = 3 * global chunk index)
                #pragma unroll
                for (int e = 0; e < E; e++)
                    if (sa[e]) {
                        float* d = ht + sb[e] * LDH + 3 * (p * PHC + sj[e]);
                        d[0] = __uint_as_float(u[e].x);
                        d[1] = __uint_as_float(u[e].y);
                        d[2] = __uint_as_float(u[e].z);
                    }
                __syncthreads();
                if (p + 1 < PH) issue(hcb, p + 1);   // overlap with compute
                // compute phase p: W in registers, h from LDS (broadcast x4)
                #pragma unroll
                for (int b = 0; b < 16; b++) {
                    const f4_t* hp = reinterpret_cast<const f4_t*>(
                        ht + b * LDH + p * PW + ks * SW);
                    float s0 = 0.f, s1 = 0.f, s2 = 0.f, s3 = 0.f;
                    #pragma unroll
                    for (int q = 0; q < NQ; q++) {
                        f4_t h4 = hp[q];
                        s0 += w[p][q].x * h4.x;
                        s1 += w[p][q].y * h4.y;
                        s2 += w[p][q].z * h4.z;
                        s3 += w[p][q].w * h4.w;
                    }
                    p_[b] += (s0 + s1) + (s2 + s3);
                }
                // no sync needed: next phase's unpack writes a disjoint ht region
            }
        }

        // ---- k-slice reduction: pbuf[ks][row*16 + b] = p_[b] ----
        {
            float* dst = pbuf + ks * PBS + row * 16;
            f4_t v0; v0.x = p_[0];  v0.y = p_[1];  v0.z = p_[2];  v0.w = p_[3];
            f4_t v1; v1.x = p_[4];  v1.y = p_[5];  v1.z = p_[6];  v1.w = p_[7];
            f4_t v2; v2.x = p_[8];  v2.y = p_[9];  v2.z = p_[10]; v2.w = p_[11];
            f4_t v3; v3.x = p_[12]; v3.y = p_[13]; v3.z = p_[14]; v3.w = p_[15];
            *reinterpret_cast<f4_t*>(dst + 0)  = v0;
            *reinterpret_cast<f4_t*>(dst + 4)  = v1;
            *reinterpret_cast<f4_t*>(dst + 8)  = v2;
            *reinterpret_cast<f4_t*>(dst + 12) = v3;
        }
        __syncthreads();
        {
            // reducer (row, b=ks): sum partials over 16 slices + xg
            float dot = xgv;
            #pragma unroll
            for (int k2 = 0; k2 < 16; k2++)
                dot += pbuf[k2 * PBS + row * 16 + ks];
            gbuf2[row * 16 + ks] = dot;
        }
        __syncthreads();

        if (t < 96) {
            int l = t >> 4, b = t & 15;
            float gi = gbuf2[(0 * CHUNK + l) * 16 + b];
            float gf = gbuf2[(1 * CHUNK + l) * 16 + b];
            float gg = gbuf2[(2 * CHUNK + l) * 16 + b];
            float go = gbuf2[(3 * CHUNK + l) * 16 + b];
            float iv = 1.f / (1.f + expf(-gi));
            float fv = 1.f / (1.f + expf(-gf));
            float gv = tanhf(gg);
            float ov = 1.f / (1.f + expf(-go));
            float c  = fv * cbuf[t] + iv * gv;
            cbuf[t]  = c;
            float hv = ov * tanhf(c);
            hv = ((h0 + l) < H) ? hv : 0.f;
            hlx[b * CHUNK + l] = hv;
            if ((h0 + l) < H)
                xout[(size_t)b * ((size_t)SS * H) + (size_t)s * H + (h0 + l)] = hv;
        }
        __syncthreads();

        if (t < 32) {                                  // pack+publish chunks
            int bq = t >> 1, cj = t & 1;
            u4_t pk;
            pk.x = __float_as_uint(hlx[bq * CHUNK + 3 * cj + 0]);
            pk.y = __float_as_uint(hlx[bq * CHUNK + 3 * cj + 1]);
            pk.z = __float_as_uint(hlx[bq * CHUNK + 3 * cj + 2]);
            pk.w = TB + (unsigned)s + 1u;
            llc_store_u4(hpb + bq * NSTR + (h0 / 3 + cj), pk);
        }
        if (s + 1 < SS) {                              // speculative phase-0 issue
            const u4_t* hcn = hx + (size_t)((s + 1) & 1) * (16 * NSTR);
            issue(hcn, 0);
        }
    }
}

// ============================ launch ============================
extern "C" void kernel_launch(void* const* d_in, const int* in_sizes, int n_in,
                              void* d_out, int out_size, void* d_ws, size_t ws_size,
                              hipStream_t stream) {
    const int*   ids  = (const int*)d_in[0];
    const float* emb  = (const float*)d_in[1];
    const float* Wih0 = (const float*)d_in[2];
    const float* Whh0 = (const float*)d_in[3];
    const float* bih0 = (const float*)d_in[4];
    const float* bhh0 = (const float*)d_in[5];
    const float* Wih1 = (const float*)d_in[6];
    const float* Whh1 = (const float*)d_in[7];
    const float* bih1 = (const float*)d_in[8];
    const float* bhh1 = (const float*)d_in[9];
    const float* Wih2 = (const float*)d_in[10];
    const float* Whh2 = (const float*)d_in[11];
    const float* bih2 = (const float*)d_in[12];
    const float* bhh2 = (const float*)d_in[13];
    float* out = (float*)d_out;

    // workspace layout (floats)
    float* ws = (float*)d_ws;
    float* xA = ws;                        // 1,228,800  (x0, later x3)
    float* xB = xA + 1228800;              // 4,710,400  (x1, later x2)
    float* xg = xB + 4710400;              // 18,841,600 (gates, reused per layer)
    u4_t*  hx = (u4_t*)(xg + 18841600);    // [2][16][NSTR] chunks = 196,608 B
    (void)in_sizes; (void)n_in; (void)out_size; (void)ws_size;

    // zero tags once per launch (graph-captured, replay-safe)
    hipMemsetAsync(hx, 0, (size_t)2 * 16 * NSTR * 16, stream);

    // LDS bytes: (16*(KP+4) + 16*388 + 384 + 96 + 96) * 4
    const size_t lds01 = (size_t)(16 * 1156 + 16 * 388 + 576) * 4;  // 101,120
    const size_t lds2  = (size_t)(16 * 388  + 16 * 388 + 576) * 4;  //  51,968

    // ---- embedding ----
    embed_kernel<<<dim3(BB * SS), dim3(256), 0, stream>>>(ids, emb, xA);

    // ---- layer 0 ----
    gemm_xw<<<dim3(72, 64), dim3(256), 0, stream>>>(xA, Wih0, xg, 4600, 300, bih0, bhh0, 1);
    lstm_rec<384, 1152, 2, 8><<<dim3(192), dim3(NT), lds01, stream>>>(Whh0, xg, xB, hx, 1150, 0u);

    // ---- layer 1 ----
    gemm_xw<<<dim3(72, 64), dim3(256), 0, stream>>>(xB, Wih1, xg, 4600, 1150, bih1, bhh1, 1);
    lstm_rec<384, 1152, 2, 8><<<dim3(192), dim3(NT), lds01, stream>>>(Whh1, xg, xB, hx, 1150, 256u);

    // ---- layer 2 ----
    gemm_xw<<<dim3(19, 64), dim3(256), 0, stream>>>(xB, Wih2, xg, 1200, 1150, bih2, bhh2, 1);
    lstm_rec<100, 384, 1, 5><<<dim3(50), dim3(NT), lds2, stream>>>(Whh2, xg, xA, hx, 300, 512u);

    // ---- tied output projection: logits = x3 @ emb^T ----
    gemm_xw<<<dim3(500, 64), dim3(256), 0, stream>>>(xA, emb, out, NVOCAB, NEMB,
                                                     nullptr, nullptr, 0);
}

// Round 7
// 10350.121 us; speedup vs baseline: 5.9531x; 5.9531x over previous
//
#include <hip/hip_runtime.h>

#define BB 16
#define SS 256
#define NVOCAB 32000
#define NEMB 300

// ---- recurrence geometry ----
#define CHUNK 6            // h-indices per block (multiple of 3: chunk-aligned publish)
#define NT 384             // threads per rec block (48 k-slices x 8 row-groups)
#define NSTR 384           // hx chunk stride per batch row

typedef float f4_t __attribute__((ext_vector_type(4)));
typedef unsigned int u4_t __attribute__((ext_vector_type(4)));

// unaligned-safe float4 global load (rows of W are only 4B-aligned when H=1150)
__device__ __forceinline__ f4_t load_f4u(const float* p) {
    f4_t v;
    __builtin_memcpy(&v, p, sizeof(f4_t));
    return v;
}

// LLC-coherent publish: 16B store (value+tag atomic at LLC) + drain inside asm
__device__ __forceinline__ void llc_store_u4_drain(u4_t* p, u4_t v) {
    asm volatile("global_store_dwordx4 %0, %1, off sc0 sc1\n\t"
                 "s_waitcnt vmcnt(0)" :: "v"(p), "v"(v) : "memory");
}

// Bundled coherent loads: 8 x dwordx4 issued and WAITED inside one asm block.
// No in-flight destination register ever crosses compiler-visible code.
__device__ __forceinline__ void llc_load8_wait(
        u4_t& u0, u4_t& u1, u4_t& u2, u4_t& u3,
        u4_t& u4v, u4_t& u5v, u4_t& u6v, u4_t& u7v,
        const u4_t* p0, const u4_t* p1, const u4_t* p2, const u4_t* p3,
        const u4_t* p4, const u4_t* p5, const u4_t* p6, const u4_t* p7) {
    asm volatile(
        "global_load_dwordx4 %0, %8, off sc0 sc1\n\t"
        "global_load_dwordx4 %1, %9, off sc0 sc1\n\t"
        "global_load_dwordx4 %2, %10, off sc0 sc1\n\t"
        "global_load_dwordx4 %3, %11, off sc0 sc1\n\t"
        "global_load_dwordx4 %4, %12, off sc0 sc1\n\t"
        "global_load_dwordx4 %5, %13, off sc0 sc1\n\t"
        "global_load_dwordx4 %6, %14, off sc0 sc1\n\t"
        "global_load_dwordx4 %7, %15, off sc0 sc1\n\t"
        "s_waitcnt vmcnt(0)"
        : "=&v"(u0), "=&v"(u1), "=&v"(u2), "=&v"(u3),
          "=&v"(u4v), "=&v"(u5v), "=&v"(u6v), "=&v"(u7v)
        : "v"(p0), "v"(p1), "v"(p2), "v"(p3),
          "v"(p4), "v"(p5), "v"(p6), "v"(p7)
        : "memory");
}

// ============================ embedding ============================
__global__ void embed_kernel(const int* __restrict__ ids,
                             const float* __restrict__ emb,
                             float* __restrict__ x0) {
    int bs = blockIdx.x;
    int id = ids[bs];
    const float* row = emb + (size_t)id * NEMB;
    float* out = x0 + (size_t)bs * NEMB;
    const float scale = 17.320508075688772f;   // sqrt(300)
    for (int e = threadIdx.x; e < NEMB; e += blockDim.x)
        out[e] = row[e] * scale;
}

// ============================ GEMM: C = A[M,K] * W[N,K]^T (+bias) ============================
#define TM 64
#define TN 64
#define KT 16
#define LDT 68

__global__ __launch_bounds__(256) void gemm_xw(
        const float* __restrict__ A, const float* __restrict__ W,
        float* __restrict__ C, int N, int K,
        const float* __restrict__ bias_i, const float* __restrict__ bias_h,
        int permuted) {
    __shared__ __align__(16) float As[KT][LDT];
    __shared__ __align__(16) float Bs[KT][LDT];
    const int n0 = blockIdx.x * TN;
    const int m0 = blockIdx.y * TM;
    const int t  = threadIdx.x;
    const int tk = t & 15;
    const int tm = t >> 4;
    const int tx = t & 15;
    const int ty = t >> 4;
    float acc[4][4] = {};

    for (int k0 = 0; k0 < K; k0 += KT) {
        int k = k0 + tk;
        bool kok = (k < K);
        #pragma unroll
        for (int i = 0; i < 4; i++) {
            int m = tm + i * 16;
            As[tk][m] = kok ? A[(size_t)(m0 + m) * K + k] : 0.f;
            int n = n0 + m;
            Bs[tk][m] = (kok && n < N) ? W[(size_t)n * K + k] : 0.f;
        }
        __syncthreads();
        #pragma unroll
        for (int kk = 0; kk < KT; kk++) {
            float4 a = *reinterpret_cast<const float4*>(&As[kk][ty * 4]);
            float4 b = *reinterpret_cast<const float4*>(&Bs[kk][tx * 4]);
            acc[0][0] += a.x * b.x; acc[0][1] += a.x * b.y; acc[0][2] += a.x * b.z; acc[0][3] += a.x * b.w;
            acc[1][0] += a.y * b.x; acc[1][1] += a.y * b.y; acc[1][2] += a.y * b.z; acc[1][3] += a.y * b.w;
            acc[2][0] += a.z * b.x; acc[2][1] += a.z * b.y; acc[2][2] += a.z * b.z; acc[2][3] += a.z * b.w;
            acc[3][0] += a.w * b.x; acc[3][1] += a.w * b.y; acc[3][2] += a.w * b.z; acc[3][3] += a.w * b.w;
        }
        __syncthreads();
    }

    #pragma unroll
    for (int i = 0; i < 4; i++) {
        int m = m0 + ty * 4 + i;
        #pragma unroll
        for (int j = 0; j < 4; j++) {
            int n = n0 + tx * 4 + j;
            if (n < N) {
                float v = acc[i][j];
                if (bias_i) v += bias_i[n] + bias_h[n];
                size_t idx;
                if (permuted) {
                    int b_ = m >> 8;        // S = 256
                    int s_ = m & 255;
                    idx = ((size_t)s_ * BB + b_) * (size_t)N + n;
                } else {
                    idx = (size_t)m * (size_t)N + n;
                }
                C[idx] = v;
            }
        }
    }
}

// ============================ persistent LSTM recurrence (v4) ============================
// Thread (ks = t>>3, rg = t&7) computes partial dots for 3 gate rows (3*rg+j)
// over k-slice [ks*SW, ks*SW+SW) for all 16 batch items.
// - W slice streamed from global (L2-resident per block) into transient regs
//   each sub-phase: zero W traffic on the LDS pipe.
// - h exchanged as 16B {h0,h1,h2,tag} chunks via sc0|sc1 ops (r4-validated);
//   staging loads are bundled issue+wait inside single asm blocks (spill-safe).
// - reduce over 48 k-slices: one shfl_xor(8) level + padded 24-slot pbuf.
template<int SW, int NCHR>
__global__ __launch_bounds__(NT, 1) void lstm_rec(
        const float* __restrict__ Whh,   // [4H][H]
        const float* __restrict__ xg,    // [S][B][4H]
        float* __restrict__ xout,        // [B][S][H]
        u4_t* __restrict__ hx,           // [2][16][NSTR] chunks
        int H, unsigned TB) {
    constexpr int KP   = 48 * SW;        // padded K (>= H)
    constexpr int LDH  = KP + 4;         // ht row stride
    constexpr int NSUB = SW / 8;         // 8-col sub-phases per slice
    constexpr int PRS  = 17;             // pbuf row stride (conflict-free)
    constexpr int PSS  = 24 * PRS + 4;   // pbuf slot stride = 412
    extern __shared__ __align__(16) float lds[];
    float* ht   = lds;                   // [16][LDH]
    float* pbuf = ht + 16 * LDH;         // [24][PSS]
    float* gbuf = pbuf + 24 * PSS;       // [NT]   (row*16+b)
    float* cbuf = gbuf + NT;             // [96]
    float* hlx  = cbuf + 96;             // [96]

    const int t    = threadIdx.x;
    const int lane = t & 63;
    const int wv   = t >> 6;             // wave 0..5
    const int ks   = t >> 3;             // 0..47
    const int rg   = t & 7;              // 0..7
    const int h0   = blockIdx.x * CHUNK;
    const int G4   = 4 * H;

    // W row pointers (invalid rows clamped to row 0; results discarded later)
    const float* wr[3];
    #pragma unroll
    for (int j = 0; j < 3; j++) {
        int r = 3 * rg + j, g = r / CHUNK, l = r - g * CHUNK;
        int grow = ((h0 + l) < H) ? (g * H + h0 + l) : 0;
        wr[j] = Whh + (size_t)grow * (size_t)H;
    }

    // zero ht (covers pad cols / never-staged region) and c state
    for (int i = t; i < 16 * LDH; i += NT) ht[i] = 0.f;
    if (t < 96) cbuf[t] = 0.f;
    __syncthreads();

    // reducer/output role: (r_row = t>>4, r_b = t&15)
    const int r_row = t >> 4, r_b = t & 15;
    const int r_g = r_row / CHUNK, r_l = r_row - r_g * CHUNK;
    const int r_h = ((h0 + r_l) < H) ? (h0 + r_l) : h0;
    const float* xgp = xg + (size_t)r_b * G4 + (size_t)r_g * H + r_h;

    const int pairidx = (lane >> 4) & 3;
    const int prow3   = 3 * (lane & 7);

    #pragma unroll 1
    for (int s = 0; s < SS; s++) {
        const u4_t* hcb = hx + (size_t)(s & 1) * (16 * NSTR);        // consume
        u4_t*       hpb = hx + (size_t)((s + 1) & 1) * (16 * NSTR);  // produce
        const unsigned tgt = TB + (unsigned)s;
        float xgv = xgp[(size_t)s * (size_t)(16 * G4)];

        // ---- stage h tile (skip at s==0: ht stays zero) ----
        if (s > 0 && t < NCHR) {
            const u4_t* cb = hcb + t;
            #pragma unroll
            for (int rh = 0; rh < 2; rh++) {
                const u4_t* q0 = cb + (rh * 8 + 0) * NSTR;
                const u4_t* q1 = cb + (rh * 8 + 1) * NSTR;
                const u4_t* q2 = cb + (rh * 8 + 2) * NSTR;
                const u4_t* q3 = cb + (rh * 8 + 3) * NSTR;
                const u4_t* q4 = cb + (rh * 8 + 4) * NSTR;
                const u4_t* q5 = cb + (rh * 8 + 5) * NSTR;
                const u4_t* q6 = cb + (rh * 8 + 6) * NSTR;
                const u4_t* q7 = cb + (rh * 8 + 7) * NSTR;
                u4_t u0, u1, u2, u3, u4v, u5v, u6v, u7v;
                for (;;) {
                    llc_load8_wait(u0, u1, u2, u3, u4v, u5v, u6v, u7v,
                                   q0, q1, q2, q3, q4, q5, q6, q7);
                    int ok = (u0.w >= tgt) & (u1.w >= tgt) & (u2.w >= tgt) & (u3.w >= tgt)
                           & (u4v.w >= tgt) & (u5v.w >= tgt) & (u6v.w >= tgt) & (u7v.w >= tgt);
                    if (ok) break;
                }
                float* d;
                d = ht + (rh * 8 + 0) * LDH + 3 * t;
                d[0] = __uint_as_float(u0.x); d[1] = __uint_as_float(u0.y); d[2] = __uint_as_float(u0.z);
                d = ht + (rh * 8 + 1) * LDH + 3 * t;
                d[0] = __uint_as_float(u1.x); d[1] = __uint_as_float(u1.y); d[2] = __uint_as_float(u1.z);
                d = ht + (rh * 8 + 2) * LDH + 3 * t;
                d[0] = __uint_as_float(u2.x); d[1] = __uint_as_float(u2.y); d[2] = __uint_as_float(u2.z);
                d = ht + (rh * 8 + 3) * LDH + 3 * t;
                d[0] = __uint_as_float(u3.x); d[1] = __uint_as_float(u3.y); d[2] = __uint_as_float(u3.z);
                d = ht + (rh * 8 + 4) * LDH + 3 * t;
                d[0] = __uint_as_float(u4v.x); d[1] = __uint_as_float(u4v.y); d[2] = __uint_as_float(u4v.z);
                d = ht + (rh * 8 + 5) * LDH + 3 * t;
                d[0] = __uint_as_float(u5v.x); d[1] = __uint_as_float(u5v.y); d[2] = __uint_as_float(u5v.z);
                d = ht + (rh * 8 + 6) * LDH + 3 * t;
                d[0] = __uint_as_float(u6v.x); d[1] = __uint_as_float(u6v.y); d[2] = __uint_as_float(u6v.z);
                d = ht + (rh * 8 + 7) * LDH + 3 * t;
                d[0] = __uint_as_float(u7v.x); d[1] = __uint_as_float(u7v.y); d[2] = __uint_as_float(u7v.z);
            }
        }
        __syncthreads();

        // ---- per-thread partial dots (W streamed from L2, h from LDS) ----
        float a[3][16];
        #pragma unroll
        for (int j = 0; j < 3; j++)
            #pragma unroll
            for (int b = 0; b < 16; b++) a[j][b] = 0.f;

        if (s > 0) {
            #pragma unroll
            for (int sub = 0; sub < NSUB; sub++) {
                const int kk = ks * SW + sub * 8;
                const int k0 = (kk < H) ? kk : 0;          // clamp (L2 tail); h=0 there
                const int k1 = (kk + 4 < H) ? (kk + 4) : 0;
                const f4_t w00 = load_f4u(wr[0] + k0), w01 = load_f4u(wr[0] + k1);
                const f4_t w10 = load_f4u(wr[1] + k0), w11 = load_f4u(wr[1] + k1);
                const f4_t w20 = load_f4u(wr[2] + k0), w21 = load_f4u(wr[2] + k1);
                const float* hb = ht + kk;
                #pragma unroll
                for (int b = 0; b < 16; b++) {
                    const f4_t h0v = *reinterpret_cast<const f4_t*>(hb + b * LDH);
                    const f4_t h1v = *reinterpret_cast<const f4_t*>(hb + b * LDH + 4);
                    float acc;
                    acc = a[0][b];
                    acc = fmaf(w00.x, h0v.x, acc); acc = fmaf(w00.y, h0v.y, acc);
                    acc = fmaf(w00.z, h0v.z, acc); acc = fmaf(w00.w, h0v.w, acc);
                    acc = fmaf(w01.x, h1v.x, acc); acc = fmaf(w01.y, h1v.y, acc);
                    acc = fmaf(w01.z, h1v.z, acc); acc = fmaf(w01.w, h1v.w, acc);
                    a[0][b] = acc;
                    acc = a[1][b];
                    acc = fmaf(w10.x, h0v.x, acc); acc = fmaf(w10.y, h0v.y, acc);
                    acc = fmaf(w10.z, h0v.z, acc); acc = fmaf(w10.w, h0v.w, acc);
                    acc = fmaf(w11.x, h1v.x, acc); acc = fmaf(w11.y, h1v.y, acc);
                    acc = fmaf(w11.z, h1v.z, acc); acc = fmaf(w11.w, h1v.w, acc);
                    a[1][b] = acc;
                    acc = a[2][b];
                    acc = fmaf(w20.x, h0v.x, acc); acc = fmaf(w20.y, h0v.y, acc);
                    acc = fmaf(w20.z, h0v.z, acc); acc = fmaf(w20.w, h0v.w, acc);
                    acc = fmaf(w21.x, h1v.x, acc); acc = fmaf(w21.y, h1v.y, acc);
                    acc = fmaf(w21.z, h1v.z, acc); acc = fmaf(w21.w, h1v.w, acc);
                    a[2][b] = acc;
                }
            }
        }

        // ---- reduce k-slices: 1 shfl level (ks pairs) -> 24-slot pbuf ----
        #pragma unroll
        for (int j = 0; j < 3; j++)
            #pragma unroll
            for (int b = 0; b < 16; b++) {
                float v = a[j][b] + __shfl_xor(a[j][b], 8);
                if ((lane & 8) == 0)
                    pbuf[(wv * 4 + pairidx) * PSS + (prow3 + j) * PRS + b] = v;
            }
        __syncthreads();

        // ---- final reduce + bias from xg ----
        {
            float dot = xgv;
            #pragma unroll
            for (int q = 0; q < 24; q++)
                dot += pbuf[q * PSS + r_row * PRS + r_b];
            gbuf[t] = dot;
        }
        __syncthreads();

        // ---- gates ----
        if (t < 96) {
            int l = t >> 4, b = t & 15;
            float gi = gbuf[(0 * CHUNK + l) * 16 + b];
            float gf = gbuf[(1 * CHUNK + l) * 16 + b];
            float gg = gbuf[(2 * CHUNK + l) * 16 + b];
            float go = gbuf[(3 * CHUNK + l) * 16 + b];
            float iv = 1.f / (1.f + expf(-gi));
            float fv = 1.f / (1.f + expf(-gf));
            float gv = tanhf(gg);
            float ov = 1.f / (1.f + expf(-go));
            float c  = fv * cbuf[t] + iv * gv;
            cbuf[t]  = c;
            float hv = ov * tanhf(c);
            hv = ((h0 + l) < H) ? hv : 0.f;
            hlx[b * CHUNK + l] = hv;
            if ((h0 + l) < H)
                xout[(size_t)b * ((size_t)SS * H) + (size_t)s * H + (h0 + l)] = hv;
        }
        __syncthreads();

        // ---- pack + publish this block's 2 chunks per batch row ----
        if (t < 32) {
            int bq = t >> 1, cj = t & 1;
            u4_t pk;
            pk.x = __float_as_uint(hlx[bq * CHUNK + 3 * cj + 0]);
            pk.y = __float_as_uint(hlx[bq * CHUNK + 3 * cj + 1]);
            pk.z = __float_as_uint(hlx[bq * CHUNK + 3 * cj + 2]);
            pk.w = tgt + 1u;
            llc_store_u4_drain(hpb + bq * NSTR + (h0 / 3 + cj), pk);
        }
    }
}

// ============================ launch ============================
extern "C" void kernel_launch(void* const* d_in, const int* in_sizes, int n_in,
                              void* d_out, int out_size, void* d_ws, size_t ws_size,
                              hipStream_t stream) {
    const int*   ids  = (const int*)d_in[0];
    const float* emb  = (const float*)d_in[1];
    const float* Wih0 = (const float*)d_in[2];
    const float* Whh0 = (const float*)d_in[3];
    const float* bih0 = (const float*)d_in[4];
    const float* bhh0 = (const float*)d_in[5];
    const float* Wih1 = (const float*)d_in[6];
    const float* Whh1 = (const float*)d_in[7];
    const float* bih1 = (const float*)d_in[8];
    const float* bhh1 = (const float*)d_in[9];
    const float* Wih2 = (const float*)d_in[10];
    const float* Whh2 = (const float*)d_in[11];
    const float* bih2 = (const float*)d_in[12];
    const float* bhh2 = (const float*)d_in[13];
    float* out = (float*)d_out;

    // workspace layout (floats)
    float* ws = (float*)d_ws;
    float* xA = ws;                        // 1,228,800  (x0, later x3)
    float* xB = xA + 1228800;              // 4,710,400  (x1, later x2)
    float* xg = xB + 4710400;              // 18,841,600 (gates, reused per layer)
    u4_t*  hx = (u4_t*)(xg + 18841600);    // [2][16][NSTR] chunks = 196,608 B
    (void)in_sizes; (void)n_in; (void)out_size; (void)ws_size;

    // zero tags once per launch (graph-captured, replay-safe)
    hipMemsetAsync(hx, 0, (size_t)2 * 16 * NSTR * 16, stream);

    // LDS bytes: (16*(48*SW+4) + 24*412 + 384 + 96 + 96) * 4
    const size_t lds01 = (size_t)(16 * 1156 + 24 * 412 + 576) * 4;  // 115,840
    const size_t lds2  = (size_t)(16 * 388  + 24 * 412 + 576) * 4;  //  66,688

    // ---- embedding ----
    embed_kernel<<<dim3(BB * SS), dim3(256), 0, stream>>>(ids, emb, xA);

    // ---- layer 0 ----
    gemm_xw<<<dim3(72, 64), dim3(256), 0, stream>>>(xA, Wih0, xg, 4600, 300, bih0, bhh0, 1);
    lstm_rec<24, 384><<<dim3(192), dim3(NT), lds01, stream>>>(Whh0, xg, xB, hx, 1150, 0u);

    // ---- layer 1 ----
    gemm_xw<<<dim3(72, 64), dim3(256), 0, stream>>>(xB, Wih1, xg, 4600, 1150, bih1, bhh1, 1);
    lstm_rec<24, 384><<<dim3(192), dim3(NT), lds01, stream>>>(Whh1, xg, xB, hx, 1150, 256u);

    // ---- layer 2 ----
    gemm_xw<<<dim3(19, 64), dim3(256), 0, stream>>>(xB, Wih2, xg, 1200, 1150, bih2, bhh2, 1);
    lstm_rec<8, 100><<<dim3(50), dim3(NT), lds2, stream>>>(Whh2, xg, xA, hx, 300, 512u);

    // ---- tied output projection: logits = x3 @ emb^T ----
    gemm_xw<<<dim3(500, 64), dim3(256), 0, stream>>>(xA, emb, out, NVOCAB, NEMB,
                                                     nullptr, nullptr, 0);
}

// Round 8
// 10134.824 us; speedup vs baseline: 6.0796x; 1.0212x over previous
//
#include <hip/hip_runtime.h>

#define BB 16
#define SS 256
#define NVOCAB 32000
#define NEMB 300

// ---- recurrence geometry ----
#define CHUNK 6            // h-indices per block (multiple of 3: chunk-aligned publish)
#define NT 384             // threads per rec block (48 k-slices x 8 row-groups)
#define NSTR 384           // hx chunk stride per batch row

typedef float f4_t __attribute__((ext_vector_type(4)));
typedef unsigned int u4_t __attribute__((ext_vector_type(4)));
typedef short bf16x8 __attribute__((ext_vector_type(8)));
typedef float f32x4 __attribute__((ext_vector_type(4)));
typedef unsigned short ushort_t;

// unaligned-safe float4 global load (rows of W are only 4B-aligned when H=1150)
__device__ __forceinline__ f4_t load_f4u(const float* p) {
    f4_t v;
    __builtin_memcpy(&v, p, sizeof(f4_t));
    return v;
}

// LLC-coherent publish: 16B store (value+tag atomic at LLC) + drain inside asm
__device__ __forceinline__ void llc_store_u4_drain(u4_t* p, u4_t v) {
    asm volatile("global_store_dwordx4 %0, %1, off sc0 sc1\n\t"
                 "s_waitcnt vmcnt(0)" :: "v"(p), "v"(v) : "memory");
}

// Bundled coherent loads: 8 x dwordx4 issued and WAITED inside one asm block.
__device__ __forceinline__ void llc_load8_wait(
        u4_t& u0, u4_t& u1, u4_t& u2, u4_t& u3,
        u4_t& u4v, u4_t& u5v, u4_t& u6v, u4_t& u7v,
        const u4_t* p0, const u4_t* p1, const u4_t* p2, const u4_t* p3,
        const u4_t* p4, const u4_t* p5, const u4_t* p6, const u4_t* p7) {
    asm volatile(
        "global_load_dwordx4 %0, %8, off sc0 sc1\n\t"
        "global_load_dwordx4 %1, %9, off sc0 sc1\n\t"
        "global_load_dwordx4 %2, %10, off sc0 sc1\n\t"
        "global_load_dwordx4 %3, %11, off sc0 sc1\n\t"
        "global_load_dwordx4 %4, %12, off sc0 sc1\n\t"
        "global_load_dwordx4 %5, %13, off sc0 sc1\n\t"
        "global_load_dwordx4 %6, %14, off sc0 sc1\n\t"
        "global_load_dwordx4 %7, %15, off sc0 sc1\n\t"
        "s_waitcnt vmcnt(0)"
        : "=&v"(u0), "=&v"(u1), "=&v"(u2), "=&v"(u3),
          "=&v"(u4v), "=&v"(u5v), "=&v"(u6v), "=&v"(u7v)
        : "v"(p0), "v"(p1), "v"(p2), "v"(p3),
          "v"(p4), "v"(p5), "v"(p6), "v"(p7)
        : "memory");
}

// single-chunk spin: reload one 16B chunk until its tag is fresh
__device__ __forceinline__ u4_t llc_spin1(const u4_t* p, unsigned tgt) {
    u4_t v;
    do {
        asm volatile("global_load_dwordx4 %0, %1, off sc0 sc1\n\t"
                     "s_waitcnt vmcnt(0)" : "=v"(v) : "v"(p) : "memory");
    } while (v.w < tgt);
    return v;
}

// ============================ embedding ============================
__global__ void embed_kernel(const int* __restrict__ ids,
                             const float* __restrict__ emb,
                             float* __restrict__ x0) {
    int bs = blockIdx.x;
    int id = ids[bs];
    const float* row = emb + (size_t)id * NEMB;
    float* out = x0 + (size_t)bs * NEMB;
    const float scale = 17.320508075688772f;   // sqrt(300)
    for (int e = threadIdx.x; e < NEMB; e += blockDim.x)
        out[e] = row[e] * scale;
}

// ============================ GEMM: C = A[M,K] * W[N,K]^T (+bias) ============================
#define TM 64
#define TN 64
#define KT 16
#define LDT 68

__global__ __launch_bounds__(256) void gemm_xw(
        const float* __restrict__ A, const float* __restrict__ W,
        float* __restrict__ C, int N, int K,
        const float* __restrict__ bias_i, const float* __restrict__ bias_h,
        int permuted) {
    __shared__ __align__(16) float As[KT][LDT];
    __shared__ __align__(16) float Bs[KT][LDT];
    const int n0 = blockIdx.x * TN;
    const int m0 = blockIdx.y * TM;
    const int t  = threadIdx.x;
    const int tk = t & 15;
    const int tm = t >> 4;
    const int tx = t & 15;
    const int ty = t >> 4;
    float acc[4][4] = {};

    for (int k0 = 0; k0 < K; k0 += KT) {
        int k = k0 + tk;
        bool kok = (k < K);
        #pragma unroll
        for (int i = 0; i < 4; i++) {
            int m = tm + i * 16;
            As[tk][m] = kok ? A[(size_t)(m0 + m) * K + k] : 0.f;
            int n = n0 + m;
            Bs[tk][m] = (kok && n < N) ? W[(size_t)n * K + k] : 0.f;
        }
        __syncthreads();
        #pragma unroll
        for (int kk = 0; kk < KT; kk++) {
            float4 a = *reinterpret_cast<const float4*>(&As[kk][ty * 4]);
            float4 b = *reinterpret_cast<const float4*>(&Bs[kk][tx * 4]);
            acc[0][0] += a.x * b.x; acc[0][1] += a.x * b.y; acc[0][2] += a.x * b.z; acc[0][3] += a.x * b.w;
            acc[1][0] += a.y * b.x; acc[1][1] += a.y * b.y; acc[1][2] += a.y * b.z; acc[1][3] += a.y * b.w;
            acc[2][0] += a.z * b.x; acc[2][1] += a.z * b.y; acc[2][2] += a.z * b.z; acc[2][3] += a.z * b.w;
            acc[3][0] += a.w * b.x; acc[3][1] += a.w * b.y; acc[3][2] += a.w * b.z; acc[3][3] += a.w * b.w;
        }
        __syncthreads();
    }

    #pragma unroll
    for (int i = 0; i < 4; i++) {
        int m = m0 + ty * 4 + i;
        #pragma unroll
        for (int j = 0; j < 4; j++) {
            int n = n0 + tx * 4 + j;
            if (n < N) {
                float v = acc[i][j];
                if (bias_i) v += bias_i[n] + bias_h[n];
                size_t idx;
                if (permuted) {
                    int b_ = m >> 8;        // S = 256
                    int s_ = m & 255;
                    idx = ((size_t)s_ * BB + b_) * (size_t)N + n;
                } else {
                    idx = (size_t)m * (size_t)N + n;
                }
                C[idx] = v;
            }
        }
    }
}

// ============================ fp32 -> bf16 hi/lo split ============================
__global__ void conv_split(const float* __restrict__ src,
                           ushort_t* __restrict__ hi, ushort_t* __restrict__ lo,
                           int K, int KP, int total) {
    for (int i = blockIdx.x * blockDim.x + threadIdx.x; i < total;
         i += gridDim.x * blockDim.x) {
        int r = i / KP, k = i - r * KP;
        float v = (k < K) ? src[(size_t)r * K + k] : 0.f;
        unsigned u = __float_as_uint(v);
        unsigned hb = (u + 0x7FFFu + ((u >> 16) & 1u)) >> 16;
        float hf = __uint_as_float(hb << 16);
        float rem = v - hf;
        unsigned u2 = __float_as_uint(rem);
        unsigned lb = (u2 + 0x7FFFu + ((u2 >> 16) & 1u)) >> 16;
        hi[i] = (ushort_t)hb;
        lo[i] = (ushort_t)lb;
    }
}

// ============================ bf16-split MFMA GEMM (tied projection) ============================
// C[4096][32000] = A[4096][320] * W[32000][320]^T via Ah*Wh + Ah*Wl + Al*Wh.
// 128x128 tile, 4 waves (2x2), each wave 64x64 = 4x4 16x16x32 fragments.
__global__ __launch_bounds__(256) void gemm_mfma(
        const ushort_t* __restrict__ Ah, const ushort_t* __restrict__ Al,
        const ushort_t* __restrict__ Wh, const ushort_t* __restrict__ Wl,
        float* __restrict__ C) {
    constexpr int KP = 320, LD = 40;   // LDS row stride 40 bf16 = 80B (16B aligned)
    __shared__ ushort_t sA[2][128 * LD];
    __shared__ ushort_t sW[2][128 * LD];
    const int t    = threadIdx.x;
    const int lane = t & 63;
    const int wave = t >> 6;
    const int wm   = wave >> 1, wn = wave & 1;
    const int n0   = blockIdx.x * 128;
    const int m0   = blockIdx.y * 128;

    f32x4 acc[4][4];
    #pragma unroll
    for (int i = 0; i < 4; i++)
        #pragma unroll
        for (int j = 0; j < 4; j++)
            acc[i][j] = (f32x4){0.f, 0.f, 0.f, 0.f};

    for (int kt = 0; kt < KP / 32; kt++) {
        __syncthreads();
        #pragma unroll
        for (int c = 0; c < 2; c++) {
            int id = t + c * 256;          // 0..511
            int r = id >> 2, kq = id & 3;
            int so = r * LD + kq * 8;
            size_t goA = (size_t)(m0 + r) * KP + kt * 32 + kq * 8;
            size_t goW = (size_t)(n0 + r) * KP + kt * 32 + kq * 8;
            *reinterpret_cast<u4_t*>(&sA[0][so]) = *reinterpret_cast<const u4_t*>(Ah + goA);
            *reinterpret_cast<u4_t*>(&sA[1][so]) = *reinterpret_cast<const u4_t*>(Al + goA);
            *reinterpret_cast<u4_t*>(&sW[0][so]) = *reinterpret_cast<const u4_t*>(Wh + goW);
            *reinterpret_cast<u4_t*>(&sW[1][so]) = *reinterpret_cast<const u4_t*>(Wl + goW);
        }
        __syncthreads();

        bf16x8 ah[4], al[4], wh[4], wl[4];
        #pragma unroll
        for (int i = 0; i < 4; i++) {
            int ro = (wm * 64 + i * 16 + (lane & 15)) * LD + (lane >> 4) * 8;
            int co = (wn * 64 + i * 16 + (lane & 15)) * LD + (lane >> 4) * 8;
            ah[i] = *reinterpret_cast<const bf16x8*>(&sA[0][ro]);
            al[i] = *reinterpret_cast<const bf16x8*>(&sA[1][ro]);
            wh[i] = *reinterpret_cast<const bf16x8*>(&sW[0][co]);
            wl[i] = *reinterpret_cast<const bf16x8*>(&sW[1][co]);
        }
        #pragma unroll
        for (int i = 0; i < 4; i++)
            #pragma unroll
            for (int j = 0; j < 4; j++) {
                acc[i][j] = __builtin_amdgcn_mfma_f32_16x16x32_bf16(ah[i], wh[j], acc[i][j], 0, 0, 0);
                acc[i][j] = __builtin_amdgcn_mfma_f32_16x16x32_bf16(ah[i], wl[j], acc[i][j], 0, 0, 0);
                acc[i][j] = __builtin_amdgcn_mfma_f32_16x16x32_bf16(al[i], wh[j], acc[i][j], 0, 0, 0);
            }
    }

    // epilogue: C/D layout col=lane&15, row=(lane>>4)*4+reg
    #pragma unroll
    for (int i = 0; i < 4; i++) {
        int row = m0 + wm * 64 + i * 16 + ((lane >> 4) << 2);
        #pragma unroll
        for (int j = 0; j < 4; j++) {
            int col = n0 + wn * 64 + j * 16 + (lane & 15);
            #pragma unroll
            for (int r2 = 0; r2 < 4; r2++)
                C[(size_t)(row + r2) * NVOCAB + col] = acc[i][j][r2];
        }
    }
}

// ============================ persistent LSTM recurrence (v4/v5) ============================
// Thread (ks = t>>3, rg = t&7): partial dots for 3 gate rows over its k-slice.
// W streamed from L2 into transient regs; h exchanged as 16B {h0,h1,h2,tag}
// chunks via sc0|sc1; bundled issue+wait staging (spill-safe).
// TGT=1 (A/B variant, requires NCHR==NT): targeted per-row retry spins instead
// of whole-bundle retries + block-staggered chunk columns.
template<int SW, int NCHR, int TGT>
__global__ __launch_bounds__(NT, 1) void lstm_rec(
        const float* __restrict__ Whh,   // [4H][H]
        const float* __restrict__ xg,    // [S][B][4H]
        float* __restrict__ xout,        // [B][S][H]
        u4_t* __restrict__ hx,           // [2][16][NSTR] chunks
        int H, unsigned TB) {
    constexpr int KP   = 48 * SW;        // padded K (>= H)
    constexpr int LDH  = KP + 4;         // ht row stride
    constexpr int NSUB = SW / 8;         // 8-col sub-phases per slice
    constexpr int PRS  = 17;             // pbuf row stride (conflict-free)
    constexpr int PSS  = 24 * PRS + 4;   // pbuf slot stride = 412
    extern __shared__ __align__(16) float lds[];
    float* ht   = lds;                   // [16][LDH]
    float* pbuf = ht + 16 * LDH;         // [24][PSS]
    float* gbuf = pbuf + 24 * PSS;       // [NT]   (row*16+b)
    float* cbuf = gbuf + NT;             // [96]
    float* hlx  = cbuf + 96;             // [96]

    const int t    = threadIdx.x;
    const int lane = t & 63;
    const int wv   = t >> 6;             // wave 0..5
    const int ks   = t >> 3;             // 0..47
    const int rg   = t & 7;              // 0..7
    const int h0   = blockIdx.x * CHUNK;
    const int G4   = 4 * H;

    // staggered chunk column (TGT only); identity otherwise
    int colT = t;
    if constexpr (TGT) {
        colT = t + (int)((blockIdx.x * 24u) % 384u);
        if (colT >= 384) colT -= 384;
    }

    // W row pointers (invalid rows clamped to row 0; results discarded later)
    const float* wr[3];
    #pragma unroll
    for (int j = 0; j < 3; j++) {
        int r = 3 * rg + j, g = r / CHUNK, l = r - g * CHUNK;
        int grow = ((h0 + l) < H) ? (g * H + h0 + l) : 0;
        wr[j] = Whh + (size_t)grow * (size_t)H;
    }

    // zero ht (covers pad cols / never-staged region) and c state
    for (int i = t; i < 16 * LDH; i += NT) ht[i] = 0.f;
    if (t < 96) cbuf[t] = 0.f;
    __syncthreads();

    // reducer/output role: (r_row = t>>4, r_b = t&15)
    const int r_row = t >> 4, r_b = t & 15;
    const int r_g = r_row / CHUNK, r_l = r_row - r_g * CHUNK;
    const int r_h = ((h0 + r_l) < H) ? (h0 + r_l) : h0;
    const float* xgp = xg + (size_t)r_b * G4 + (size_t)r_g * H + r_h;

    const int pairidx = (lane >> 4) & 3;
    const int prow3   = 3 * (lane & 7);

    #pragma unroll 1
    for (int s = 0; s < SS; s++) {
        const u4_t* hcb = hx + (size_t)(s & 1) * (16 * NSTR);        // consume
        u4_t*       hpb = hx + (size_t)((s + 1) & 1) * (16 * NSTR);  // produce
        const unsigned tgt = TB + (unsigned)s;
        float xgv = xgp[(size_t)s * (size_t)(16 * G4)];

        // ---- stage h tile (skip at s==0: ht stays zero) ----
        if constexpr (TGT) {
            if (s > 0) {
                const u4_t* cb = hcb + colT;
                #pragma unroll
                for (int rh = 0; rh < 2; rh++) {
                    const u4_t* q0 = cb + (rh * 8 + 0) * NSTR;
                    const u4_t* q1 = cb + (rh * 8 + 1) * NSTR;
                    const u4_t* q2 = cb + (rh * 8 + 2) * NSTR;
                    const u4_t* q3 = cb + (rh * 8 + 3) * NSTR;
                    const u4_t* q4 = cb + (rh * 8 + 4) * NSTR;
                    const u4_t* q5 = cb + (rh * 8 + 5) * NSTR;
                    const u4_t* q6 = cb + (rh * 8 + 6) * NSTR;
                    const u4_t* q7 = cb + (rh * 8 + 7) * NSTR;
                    u4_t u0, u1, u2, u3, u4v, u5v, u6v, u7v;
                    llc_load8_wait(u0, u1, u2, u3, u4v, u5v, u6v, u7v,
                                   q0, q1, q2, q3, q4, q5, q6, q7);
                    if (u0.w  < tgt) u0  = llc_spin1(q0, tgt);
                    if (u1.w  < tgt) u1  = llc_spin1(q1, tgt);
                    if (u2.w  < tgt) u2  = llc_spin1(q2, tgt);
                    if (u3.w  < tgt) u3  = llc_spin1(q3, tgt);
                    if (u4v.w < tgt) u4v = llc_spin1(q4, tgt);
                    if (u5v.w < tgt) u5v = llc_spin1(q5, tgt);
                    if (u6v.w < tgt) u6v = llc_spin1(q6, tgt);
                    if (u7v.w < tgt) u7v = llc_spin1(q7, tgt);
                    float* d;
                    d = ht + (rh * 8 + 0) * LDH + 3 * colT;
                    d[0] = __uint_as_float(u0.x); d[1] = __uint_as_float(u0.y); d[2] = __uint_as_float(u0.z);
                    d = ht + (rh * 8 + 1) * LDH + 3 * colT;
                    d[0] = __uint_as_float(u1.x); d[1] = __uint_as_float(u1.y); d[2] = __uint_as_float(u1.z);
                    d = ht + (rh * 8 + 2) * LDH + 3 * colT;
                    d[0] = __uint_as_float(u2.x); d[1] = __uint_as_float(u2.y); d[2] = __uint_as_float(u2.z);
                    d = ht + (rh * 8 + 3) * LDH + 3 * colT;
                    d[0] = __uint_as_float(u3.x); d[1] = __uint_as_float(u3.y); d[2] = __uint_as_float(u3.z);
                    d = ht + (rh * 8 + 4) * LDH + 3 * colT;
                    d[0] = __uint_as_float(u4v.x); d[1] = __uint_as_float(u4v.y); d[2] = __uint_as_float(u4v.z);
                    d = ht + (rh * 8 + 5) * LDH + 3 * colT;
                    d[0] = __uint_as_float(u5v.x); d[1] = __uint_as_float(u5v.y); d[2] = __uint_as_float(u5v.z);
                    d = ht + (rh * 8 + 6) * LDH + 3 * colT;
                    d[0] = __uint_as_float(u6v.x); d[1] = __uint_as_float(u6v.y); d[2] = __uint_as_float(u6v.z);
                    d = ht + (rh * 8 + 7) * LDH + 3 * colT;
                    d[0] = __uint_as_float(u7v.x); d[1] = __uint_as_float(u7v.y); d[2] = __uint_as_float(u7v.z);
                }
            }
        } else {
            if (s > 0 && t < NCHR) {
                const u4_t* cb = hcb + t;
                #pragma unroll
                for (int rh = 0; rh < 2; rh++) {
                    const u4_t* q0 = cb + (rh * 8 + 0) * NSTR;
                    const u4_t* q1 = cb + (rh * 8 + 1) * NSTR;
                    const u4_t* q2 = cb + (rh * 8 + 2) * NSTR;
                    const u4_t* q3 = cb + (rh * 8 + 3) * NSTR;
                    const u4_t* q4 = cb + (rh * 8 + 4) * NSTR;
                    const u4_t* q5 = cb + (rh * 8 + 5) * NSTR;
                    const u4_t* q6 = cb + (rh * 8 + 6) * NSTR;
                    const u4_t* q7 = cb + (rh * 8 + 7) * NSTR;
                    u4_t u0, u1, u2, u3, u4v, u5v, u6v, u7v;
                    for (;;) {
                        llc_load8_wait(u0, u1, u2, u3, u4v, u5v, u6v, u7v,
                                       q0, q1, q2, q3, q4, q5, q6, q7);
                        int ok = (u0.w >= tgt) & (u1.w >= tgt) & (u2.w >= tgt) & (u3.w >= tgt)
                               & (u4v.w >= tgt) & (u5v.w >= tgt) & (u6v.w >= tgt) & (u7v.w >= tgt);
                        if (ok) break;
                    }
                    float* d;
                    d = ht + (rh * 8 + 0) * LDH + 3 * t;
                    d[0] = __uint_as_float(u0.x); d[1] = __uint_as_float(u0.y); d[2] = __uint_as_float(u0.z);
                    d = ht + (rh * 8 + 1) * LDH + 3 * t;
                    d[0] = __uint_as_float(u1.x); d[1] = __uint_as_float(u1.y); d[2] = __uint_as_float(u1.z);
                    d = ht + (rh * 8 + 2) * LDH + 3 * t;
                    d[0] = __uint_as_float(u2.x); d[1] = __uint_as_float(u2.y); d[2] = __uint_as_float(u2.z);
                    d = ht + (rh * 8 + 3) * LDH + 3 * t;
                    d[0] = __uint_as_float(u3.x); d[1] = __uint_as_float(u3.y); d[2] = __uint_as_float(u3.z);
                    d = ht + (rh * 8 + 4) * LDH + 3 * t;
                    d[0] = __uint_as_float(u4v.x); d[1] = __uint_as_float(u4v.y); d[2] = __uint_as_float(u4v.z);
                    d = ht + (rh * 8 + 5) * LDH + 3 * t;
                    d[0] = __uint_as_float(u5v.x); d[1] = __uint_as_float(u5v.y); d[2] = __uint_as_float(u5v.z);
                    d = ht + (rh * 8 + 6) * LDH + 3 * t;
                    d[0] = __uint_as_float(u6v.x); d[1] = __uint_as_float(u6v.y); d[2] = __uint_as_float(u6v.z);
                    d = ht + (rh * 8 + 7) * LDH + 3 * t;
                    d[0] = __uint_as_float(u7v.x); d[1] = __uint_as_float(u7v.y); d[2] = __uint_as_float(u7v.z);
                }
            }
        }
        __syncthreads();

        // ---- per-thread partial dots (W streamed from L2, h from LDS) ----
        float a[3][16];
        #pragma unroll
        for (int j = 0; j < 3; j++)
            #pragma unroll
            for (int b = 0; b < 16; b++) a[j][b] = 0.f;

        if (s > 0) {
            #pragma unroll
            for (int sub = 0; sub < NSUB; sub++) {
                const int kk = ks * SW + sub * 8;
                const int k0 = (kk < H) ? kk : 0;          // clamp (L2 tail); h=0 there
                const int k1 = (kk + 4 < H) ? (kk + 4) : 0;
                const f4_t w00 = load_f4u(wr[0] + k0), w01 = load_f4u(wr[0] + k1);
                const f4_t w10 = load_f4u(wr[1] + k0), w11 = load_f4u(wr[1] + k1);
                const f4_t w20 = load_f4u(wr[2] + k0), w21 = load_f4u(wr[2] + k1);
                const float* hb = ht + kk;
                #pragma unroll
                for (int b = 0; b < 16; b++) {
                    const f4_t h0v = *reinterpret_cast<const f4_t*>(hb + b * LDH);
                    const f4_t h1v = *reinterpret_cast<const f4_t*>(hb + b * LDH + 4);
                    float acc;
                    acc = a[0][b];
                    acc = fmaf(w00.x, h0v.x, acc); acc = fmaf(w00.y, h0v.y, acc);
                    acc = fmaf(w00.z, h0v.z, acc); acc = fmaf(w00.w, h0v.w, acc);
                    acc = fmaf(w01.x, h1v.x, acc); acc = fmaf(w01.y, h1v.y, acc);
                    acc = fmaf(w01.z, h1v.z, acc); acc = fmaf(w01.w, h1v.w, acc);
                    a[0][b] = acc;
                    acc = a[1][b];
                    acc = fmaf(w10.x, h0v.x, acc); acc = fmaf(w10.y, h0v.y, acc);
                    acc = fmaf(w10.z, h0v.z, acc); acc = fmaf(w10.w, h0v.w, acc);
                    acc = fmaf(w11.x, h1v.x, acc); acc = fmaf(w11.y, h1v.y, acc);
                    acc = fmaf(w11.z, h1v.z, acc); acc = fmaf(w11.w, h1v.w, acc);
                    a[1][b] = acc;
                    acc = a[2][b];
                    acc = fmaf(w20.x, h0v.x, acc); acc = fmaf(w20.y, h0v.y, acc);
                    acc = fmaf(w20.z, h0v.z, acc); acc = fmaf(w20.w, h0v.w, acc);
                    acc = fmaf(w21.x, h1v.x, acc); acc = fmaf(w21.y, h1v.y, acc);
                    acc = fmaf(w21.z, h1v.z, acc); acc = fmaf(w21.w, h1v.w, acc);
                    a[2][b] = acc;
                }
            }
        }

        // ---- reduce k-slices: 1 shfl level (ks pairs) -> 24-slot pbuf ----
        #pragma unroll
        for (int j = 0; j < 3; j++)
            #pragma unroll
            for (int b = 0; b < 16; b++) {
                float v = a[j][b] + __shfl_xor(a[j][b], 8);
                if ((lane & 8) == 0)
                    pbuf[(wv * 4 + pairidx) * PSS + (prow3 + j) * PRS + b] = v;
            }
        __syncthreads();

        // ---- final reduce + bias from xg ----
        {
            float dot = xgv;
            #pragma unroll
            for (int q = 0; q < 24; q++)
                dot += pbuf[q * PSS + r_row * PRS + r_b];
            gbuf[t] = dot;
        }
        __syncthreads();

        // ---- gates ----
        if (t < 96) {
            int l = t >> 4, b = t & 15;
            float gi = gbuf[(0 * CHUNK + l) * 16 + b];
            float gf = gbuf[(1 * CHUNK + l) * 16 + b];
            float gg = gbuf[(2 * CHUNK + l) * 16 + b];
            float go = gbuf[(3 * CHUNK + l) * 16 + b];
            float iv = 1.f / (1.f + expf(-gi));
            float fv = 1.f / (1.f + expf(-gf));
            float gv = tanhf(gg);
            float ov = 1.f / (1.f + expf(-go));
            float c  = fv * cbuf[t] + iv * gv;
            cbuf[t]  = c;
            float hv = ov * tanhf(c);
            hv = ((h0 + l) < H) ? hv : 0.f;
            hlx[b * CHUNK + l] = hv;
            if ((h0 + l) < H)
                xout[(size_t)b * ((size_t)SS * H) + (size_t)s * H + (h0 + l)] = hv;
        }
        __syncthreads();

        // ---- pack + publish this block's 2 chunks per batch row ----
        if (t < 32) {
            int bq = t >> 1, cj = t & 1;
            u4_t pk;
            pk.x = __float_as_uint(hlx[bq * CHUNK + 3 * cj + 0]);
            pk.y = __float_as_uint(hlx[bq * CHUNK + 3 * cj + 1]);
            pk.z = __float_as_uint(hlx[bq * CHUNK + 3 * cj + 2]);
            pk.w = tgt + 1u;
            llc_store_u4_drain(hpb + bq * NSTR + (h0 / 3 + cj), pk);
        }
    }
}

// ============================ launch ============================
extern "C" void kernel_launch(void* const* d_in, const int* in_sizes, int n_in,
                              void* d_out, int out_size, void* d_ws, size_t ws_size,
                              hipStream_t stream) {
    const int*   ids  = (const int*)d_in[0];
    const float* emb  = (const float*)d_in[1];
    const float* Wih0 = (const float*)d_in[2];
    const float* Whh0 = (const float*)d_in[3];
    const float* bih0 = (const float*)d_in[4];
    const float* bhh0 = (const float*)d_in[5];
    const float* Wih1 = (const float*)d_in[6];
    const float* Whh1 = (const float*)d_in[7];
    const float* bih1 = (const float*)d_in[8];
    const float* bhh1 = (const float*)d_in[9];
    const float* Wih2 = (const float*)d_in[10];
    const float* Whh2 = (const float*)d_in[11];
    const float* bih2 = (const float*)d_in[12];
    const float* bhh2 = (const float*)d_in[13];
    float* out = (float*)d_out;

    // workspace layout (floats)
    float* ws = (float*)d_ws;
    float* xA = ws;                        // 1,228,800  (x0, later x3)
    float* xB = xA + 1228800;              // 4,710,400  (x1, later x2; then Ah/Al)
    float* xg = xB + 4710400;              // 18,841,600 (gates; then Wh/Wl)
    u4_t*  hx = (u4_t*)(xg + 18841600);    // [2][16][NSTR] chunks = 196,608 B
    (void)in_sizes; (void)n_in; (void)out_size; (void)ws_size;

    // bf16-split buffers in regions dead after layer-2 recurrence
    ushort_t* Ah = (ushort_t*)xB;                  // [4096][320]
    ushort_t* Al = Ah + (size_t)4096 * 320;
    ushort_t* Wh = (ushort_t*)xg;                  // [32000][320]
    ushort_t* Wl = Wh + (size_t)32000 * 320;

    // zero tags once per launch (graph-captured, replay-safe)
    hipMemsetAsync(hx, 0, (size_t)2 * 16 * NSTR * 16, stream);

    // LDS bytes: (16*(48*SW+4) + 24*412 + 384 + 96 + 96) * 4
    const size_t lds01 = (size_t)(16 * 1156 + 24 * 412 + 576) * 4;  // 115,840
    const size_t lds2  = (size_t)(16 * 388  + 24 * 412 + 576) * 4;  //  66,688

    // ---- embedding ----
    embed_kernel<<<dim3(BB * SS), dim3(256), 0, stream>>>(ids, emb, xA);

    // ---- layer 0 ----
    gemm_xw<<<dim3(72, 64), dim3(256), 0, stream>>>(xA, Wih0, xg, 4600, 300, bih0, bhh0, 1);
    lstm_rec<24, 384, 0><<<dim3(192), dim3(NT), lds01, stream>>>(Whh0, xg, xB, hx, 1150, 0u);

    // ---- layer 1 (targeted-retry staging variant: A/B vs layer 0) ----
    gemm_xw<<<dim3(72, 64), dim3(256), 0, stream>>>(xB, Wih1, xg, 4600, 1150, bih1, bhh1, 1);
    lstm_rec<24, 384, 1><<<dim3(192), dim3(NT), lds01, stream>>>(Whh1, xg, xB, hx, 1150, 256u);

    // ---- layer 2 ----
    gemm_xw<<<dim3(19, 64), dim3(256), 0, stream>>>(xB, Wih2, xg, 1200, 1150, bih2, bhh2, 1);
    lstm_rec<8, 100, 0><<<dim3(50), dim3(NT), lds2, stream>>>(Whh2, xg, xA, hx, 300, 512u);

    // ---- bf16 hi/lo conversions (xB/xg now dead) ----
    conv_split<<<dim3(640), dim3(256), 0, stream>>>(xA, Ah, Al, 300, 320, 4096 * 320);
    conv_split<<<dim3(2048), dim3(256), 0, stream>>>(emb, Wh, Wl, 300, 320, 32000 * 320);

    // ---- tied output projection via bf16-split MFMA ----
    gemm_mfma<<<dim3(250, 32), dim3(256), 0, stream>>>(Ah, Al, Wh, Wl, out);
}